// Round 5
// baseline (635.341 us; speedup 1.0000x reference)
//
#include <hip/hip_runtime.h>
#include <hip/hip_bf16.h>

#define EPS_NORM 1e-12f
#define EPS_SM   1e-16f

typedef float f32x4 __attribute__((ext_vector_type(4)));

// ======================= CSR build =======================

// one atomic edge pass: position within dst segment + degree histogram for free
__global__ __launch_bounds__(256) void k_pos(const int* __restrict__ dst,
        int* __restrict__ deg, int* __restrict__ epos, int E) {
    int e = blockIdx.x * 256 + threadIdx.x;
    if (e >= E) return;
    int d = __builtin_nontemporal_load(&dst[e]);
    epos[e] = atomicAdd(&deg[d], 1);
}

// block-level exclusive scan over 1024-element tiles (Hillis-Steele in LDS)
__global__ __launch_bounds__(1024) void k_scan_block(const int* __restrict__ deg,
        int* __restrict__ offs, int* __restrict__ partial, int N) {
    __shared__ int sm[1024];
    int t = threadIdx.x;
    int g = blockIdx.x * 1024 + t;
    int v = (g < N) ? deg[g] : 0;
    sm[t] = v;
    __syncthreads();
    for (int d = 1; d < 1024; d <<= 1) {
        int tv = (t >= d) ? sm[t - d] : 0;
        __syncthreads();
        sm[t] += tv;
        __syncthreads();
    }
    if (g < N) offs[g] = sm[t] - v;                 // exclusive
    if (t == 1023) partial[blockIdx.x] = sm[1023];  // block total
}

// parallel exclusive scan of up to 128 block totals (single block)
__global__ __launch_bounds__(128) void k_scan_partial(int* __restrict__ partial, int nb) {
    __shared__ int sm[128];
    int t = threadIdx.x;
    int v = (t < nb) ? partial[t] : 0;
    sm[t] = v;
    __syncthreads();
    for (int d = 1; d < 128; d <<= 1) {
        int tv = (t >= d) ? sm[t - d] : 0;
        __syncthreads();
        sm[t] += tv;
        __syncthreads();
    }
    if (t < nb) partial[t] = sm[t] - v;             // exclusive
}

__global__ __launch_bounds__(256) void k_add_off(int* __restrict__ offs,
        const int* __restrict__ partial, int N, int E) {
    int g = blockIdx.x * 256 + threadIdx.x;
    if (g < N) offs[g] += partial[g >> 10];
    if (g == 0) offs[N] = E;                        // sentinel for last segment
}

// scatter without atomics; nt store (no line merging happens anyway — round-3 PMC)
__global__ __launch_bounds__(256) void k_fill(const int* __restrict__ src,
        const int* __restrict__ dst, const int* __restrict__ epos,
        const int* __restrict__ offs, int* __restrict__ csr, int E) {
    int e = blockIdx.x * 256 + threadIdx.x;
    if (e >= E) return;
    int d = __builtin_nontemporal_load(&dst[e]);
    int s = __builtin_nontemporal_load(&src[e]);
    int p = __builtin_nontemporal_load(&epos[e]);
    __builtin_nontemporal_store(s, &csr[offs[d] + p]);
}

// ======================= h = relu(x @ W1 + b1), + inv-norm of h =======================
// block = 256 thr = 4 waves; tile = 16 rows. Stage x-tile in LDS (coalesced 1KB/instr
// global loads), compute with 2x2 register tile, waves split K 4-ways, LDS reduce.
__global__ __launch_bounds__(256) void k_gemm1(const float* __restrict__ x,
        const float* __restrict__ W1, const float* __restrict__ b1,
        float* __restrict__ h, float* __restrict__ invn, int N) {
    __shared__ __align__(16) float w1t[16 * 516];   // W1 transposed, pad 512->516
    __shared__ __align__(16) float xs[16 * 516];    // x tile, pad 512->516
    __shared__ float red[4 * 256];                  // cross-wave partials
    int t = threadIdx.x;
    int wave = t >> 6, lane = t & 63;

    // stage W1 transposed (8192 floats)
    for (int idx = t; idx < 8192; idx += 256) {
        int k = idx >> 4, c = idx & 15;
        w1t[c * 516 + k] = W1[idx];
    }
    // stage x tile: 2048 float4, fully coalesced, nt (x is read exactly once)
    int row0 = blockIdx.x * 16;
    int nf4 = (N - row0 >= 16 ? 16 : N - row0) * 128;
    const f32x4* gx = (const f32x4*)(x + (size_t)row0 * 512);
#pragma unroll
    for (int j = 0; j < 8; ++j) {
        int idx = t + j * 256;                      // float4 index within tile
        if (idx < nf4) {
            f32x4 v = __builtin_nontemporal_load(&gx[idx]);
            int row = idx >> 7, kq = idx & 127;
            *(f32x4*)(xs + row * 516 + kq * 4) = v;
        }
    }
    __syncthreads();

    // compute: lane (i,j) -> rows {i,i+8} x cols {j,j+8}; this wave's K-range
    int i = lane >> 3, j = lane & 7;
    const float* xA = xs  + i * 516;
    const float* xB = xs  + (i + 8) * 516;
    const float* wA = w1t + j * 516;
    const float* wB = w1t + (j + 8) * 516;
    int k0 = wave * 128;
    float acc00 = 0.f, acc01 = 0.f, acc10 = 0.f, acc11 = 0.f;
#pragma unroll 4
    for (int kq = 0; kq < 32; ++kq) {
        int k = k0 + kq * 4;
        f32x4 a = *(const f32x4*)(xA + k);
        f32x4 b = *(const f32x4*)(xB + k);
        f32x4 u = *(const f32x4*)(wA + k);
        f32x4 v = *(const f32x4*)(wB + k);
        acc00 += a.x*u.x + a.y*u.y + a.z*u.z + a.w*u.w;
        acc01 += a.x*v.x + a.y*v.y + a.z*v.z + a.w*v.w;
        acc10 += b.x*u.x + b.y*u.y + b.z*u.z + b.w*u.w;
        acc11 += b.x*v.x + b.y*v.y + b.z*v.z + b.w*v.w;
    }
    red[wave * 256 + i * 16 + j]             = acc00;
    red[wave * 256 + i * 16 + (j + 8)]       = acc01;
    red[wave * 256 + (i + 8) * 16 + j]       = acc10;
    red[wave * 256 + (i + 8) * 16 + (j + 8)] = acc11;
    __syncthreads();

    // epilogue: thread t -> (r = t>>4, c = t&15); sum 4 wave partials
    int r = t >> 4, c = t & 15;
    int rc = r * 16 + c;
    float sum = red[rc] + red[256 + rc] + red[512 + rc] + red[768 + rc];
    int row = row0 + r;
    float val = fmaxf(sum + b1[c], 0.f);
    if (row < N) h[(size_t)row * 16 + c] = val;
    float ss = val * val;
    ss += __shfl_xor(ss, 1); ss += __shfl_xor(ss, 2);
    ss += __shfl_xor(ss, 4); ss += __shfl_xor(ss, 8);
    if (c == 0 && row < N) invn[row] = 1.f / fmaxf(sqrtf(ss), EPS_NORM);
}

// ======================= fused AGNN layer (CSR gather, no atomics) =======================
// one wave per dst node; lane = (edge_slot g<<4) | feature k; 8 edges per iteration
__global__ __launch_bounds__(256) void k_agnn(const float* __restrict__ f,
        const float* __restrict__ inv, const int* __restrict__ offs,
        const int* __restrict__ csr, const float* __restrict__ beta,
        float* __restrict__ fout, float* __restrict__ invout, int N) {
    int wid = (blockIdx.x * 256 + threadIdx.x) >> 6;   // node id (uniform per wave)
    if (wid >= N) return;
    int lane = threadIdx.x & 63;
    int g = lane >> 4, k = lane & 15;

    float fd  = f[(size_t)wid * 16 + k];
    float ivd = inv[wid];
    float b   = beta[0];

    // self-loop weight: exp(b * <xn,xn>)
    float sd = fd * fd;
    sd += __shfl_xor(sd, 1); sd += __shfl_xor(sd, 2);
    sd += __shfl_xor(sd, 4); sd += __shfl_xor(sd, 8);
    float pself = __expf(b * sd * ivd * ivd);
    float bs = b * ivd;                       // fold dst inv-norm into the scale

    int start = offs[wid];
    int end   = offs[wid + 1];

    float sacc = 0.f, gacc = 0.f;
    for (int e = start + g; e < end; e += 8) {     // this group's residues {g, g+4} mod 8
        int  e1 = e + 4;
        bool v1 = e1 < end;
        int  si0 = csr[e];
        int  si1 = v1 ? csr[e1] : si0;
        float a0 = f[(size_t)si0 * 16 + k];
        float a1 = f[(size_t)si1 * 16 + k];
        float iv0 = inv[si0];
        float iv1 = inv[si1];
        float d0 = a0 * fd, d1 = a1 * fd;
        d0 += __shfl_xor(d0, 1); d1 += __shfl_xor(d1, 1);
        d0 += __shfl_xor(d0, 2); d1 += __shfl_xor(d1, 2);
        d0 += __shfl_xor(d0, 4); d1 += __shfl_xor(d1, 4);
        d0 += __shfl_xor(d0, 8); d1 += __shfl_xor(d1, 8);
        float p0 = __expf(bs * iv0 * d0);
        float p1 = v1 ? __expf(bs * iv1 * d1) : 0.f;
        sacc += p0 + p1;
        gacc += p0 * a0 + p1 * a1;
    }
    // combine the 4 edge-slot groups (values uniform within each 16-lane group)
    sacc += __shfl_xor(sacc, 16); sacc += __shfl_xor(sacc, 32);
    gacc += __shfl_xor(gacc, 16); gacc += __shfl_xor(gacc, 32);

    float denom = sacc + pself + EPS_SM;
    float outk  = (gacc + pself * fd) / denom;

    // next layer's inverse norm from the freshly computed row
    float ss = outk * outk;
    ss += __shfl_xor(ss, 1); ss += __shfl_xor(ss, 2);
    ss += __shfl_xor(ss, 4); ss += __shfl_xor(ss, 8);

    if (g == 0) {
        fout[(size_t)wid * 16 + k] = outk;
        if (k == 0) invout[wid] = 1.f / fmaxf(sqrtf(ss), EPS_NORM);
    }
}

// ======================= out = softmax(f @ W2 + b2) =======================
__global__ __launch_bounds__(256) void k_out(const float* __restrict__ f,
        const float* __restrict__ W2, const float* __restrict__ b2,
        float* __restrict__ out, int N) {
    __shared__ float w2s[16 * 40];
    __shared__ float b2s[40];
    for (int idx = threadIdx.x; idx < 16 * 40; idx += 256) w2s[idx] = W2[idx];
    if (threadIdx.x < 40) b2s[threadIdx.x] = b2[threadIdx.x];
    __syncthreads();
    int i = blockIdx.x * 256 + threadIdx.x;
    if (i >= N) return;
    const float4* fr = (const float4*)(f + (size_t)i * 16);
    float4 q0 = fr[0], q1 = fr[1], q2 = fr[2], q3 = fr[3];
    float fv[16] = {q0.x, q0.y, q0.z, q0.w, q1.x, q1.y, q1.z, q1.w,
                    q2.x, q2.y, q2.z, q2.w, q3.x, q3.y, q3.z, q3.w};
    float z[40];
#pragma unroll
    for (int c = 0; c < 40; ++c) z[c] = b2s[c];
#pragma unroll
    for (int k = 0; k < 16; ++k) {
        float fk = fv[k];
#pragma unroll
        for (int c = 0; c < 40; ++c) z[c] += fk * w2s[k * 40 + c];
    }
    float m = z[0];
#pragma unroll
    for (int c = 1; c < 40; ++c) m = fmaxf(m, z[c]);
    float ssum = 0.f;
#pragma unroll
    for (int c = 0; c < 40; ++c) { z[c] = __expf(z[c] - m); ssum += z[c]; }
    float is = 1.f / ssum;
    float* orow = out + (size_t)i * 40;
#pragma unroll
    for (int c = 0; c < 40; ++c) orow[c] = z[c] * is;
}

extern "C" void kernel_launch(void* const* d_in, const int* in_sizes, int n_in,
                              void* d_out, int out_size, void* d_ws, size_t ws_size,
                              hipStream_t stream) {
    const float* x    = (const float*)d_in[0];
    const int*   eidx = (const int*)d_in[1];      // harness pushes integer inputs as int32
    const float* W1   = (const float*)d_in[2];
    const float* b1   = (const float*)d_in[3];
    const float* beta[3] = {(const float*)d_in[4], (const float*)d_in[5],
                            (const float*)d_in[6]};
    const float* W2   = (const float*)d_in[7];
    const float* b2   = (const float*)d_in[8];
    float*       out  = (float*)d_out;

    const int FIN = 512, H = 16;
    int N = in_sizes[0] / FIN;
    int E = in_sizes[1] / 2;

    const int* src = eidx;          // edge_index[0]
    const int* dst = eidx + E;      // edge_index[1]

    // workspace layout
    size_t nfeat = (size_t)N * H;
    float* f0      = (float*)d_ws;          // N*16
    float* f1      = f0 + nfeat;            // N*16
    float* inv0    = f1 + nfeat;            // N
    float* inv1    = inv0 + N;              // N
    int*   offs    = (int*)(inv1 + N);      // N+1
    int*   degb    = offs + (N + 1);        // N
    int*   partial = degb + N;              // 128
    int*   epos    = partial + 128;         // E
    int*   csr     = epos + E;              // E

    int nb = (N + 1023) / 1024;

    // ---- CSR build (once per launch; same graph for all 3 layers)
    hipMemsetAsync(degb, 0, (size_t)N * 4, stream);
    k_pos<<<dim3((E + 255) / 256), dim3(256), 0, stream>>>(dst, degb, epos, E);
    k_scan_block<<<dim3(nb), dim3(1024), 0, stream>>>(degb, offs, partial, N);
    k_scan_partial<<<dim3(1), dim3(128), 0, stream>>>(partial, nb);
    k_add_off<<<dim3((N + 255) / 256), dim3(256), 0, stream>>>(offs, partial, N, E);
    k_fill<<<dim3((E + 255) / 256), dim3(256), 0, stream>>>(src, dst, epos, offs, csr, E);

    // ---- MLP in + 3 fused AGNN layers + MLP out
    k_gemm1<<<dim3((N + 15) / 16), dim3(256), 0, stream>>>(x, W1, b1, f0, inv0, N);

    float* fin = f0;  float* fout = f1;
    float* ivi = inv0; float* ivo = inv1;
    for (int l = 0; l < 3; ++l) {
        k_agnn<<<dim3((N + 3) / 4), dim3(256), 0, stream>>>(
            fin, ivi, offs, csr, beta[l], fout, ivo, N);
        float* t = fin; fin = fout; fout = t;
        t = ivi; ivi = ivo; ivo = t;
    }
    k_out<<<dim3((N + 255) / 256), dim3(256), 0, stream>>>(fin, W2, b2, out, N);
}